// Round 16
// baseline (292.854 us; speedup 1.0000x reference)
//
#include <hip/hip_runtime.h>
#include <hip/hip_bf16.h>

#define N_NODES 100000
#define E_NUM   1600000
#define IN_DIM  128
#define HID     64
#define NCLS    40
#define NBUCK   782      // ceil(N_NODES/128); bucket b owns nodes [b*128, b*128+128)
#define TILE_E  2048     // small tiles -> 782 blocks -> ~3 blocks/CU (r15: 196 starved)
#define NTILE   782      // ceil(E_NUM / TILE_E)
#define BCAP    3072     // per-bucket capacity incl. pad-to-8
#define ZROW    N_NODES  // sentinel node whose H row is all zeros
#define NTILES_M 6250    // N_NODES / 16

typedef __attribute__((ext_vector_type(8))) short bf16x8;
typedef __attribute__((ext_vector_type(4))) float f32x4;

// bf16 helpers
static __device__ __forceinline__ float bflo(unsigned u) {
    return __uint_as_float(u << 16);
}
static __device__ __forceinline__ float bfhi(unsigned u) {
    return __uint_as_float(u & 0xFFFF0000u);
}
static __device__ __forceinline__ unsigned short f2bf(float f) {
    unsigned u = __float_as_uint(f);
    u += 0x7FFFu + ((u >> 16) & 1u);     // round-to-nearest-even
    return (unsigned short)(u >> 16);
}
static __device__ __forceinline__ unsigned pack2bf(float lo, float hi) {
    return (unsigned)f2bf(lo) | ((unsigned)f2bf(hi) << 16);
}

// ------ k_prep: pre-swizzle ALL weights into B-fragment order + init -------
// frag[nt][ks][lane][jp] packs W[k..k+1][n], n = nt*16+(lane&15),
// k = ks*32+(lane>>4)*8+jp*2  (r13/r14-verified layout).
// Block 0 additionally zeroes bucket cursors and the sentinel H rows.
__global__ void k_prep(const float* __restrict__ Win, const float* __restrict__ Wl,
                       const float* __restrict__ Wc, unsigned* __restrict__ pWin,
                       unsigned* __restrict__ pWl, unsigned* __restrict__ pWc,
                       int* __restrict__ cursor, unsigned short* __restrict__ H0,
                       unsigned short* __restrict__ H1)
{
    const int t = threadIdx.x;
    if (blockIdx.x == 0) {
        for (int i = t; i < NBUCK; i += 256) cursor[i] = 0;
        if (t < 32) {
            ((unsigned*)(H0 + (size_t)ZROW * HID))[t] = 0;
            ((unsigned*)(H1 + (size_t)ZROW * HID))[t] = 0;
        }
    }
    int i = blockIdx.x * 256 + t;
    if (i < 4096) {                       // W_in: 4 ntiles x 4 ksteps
        const int nt = i >> 10, ks = (i >> 8) & 3, ln = (i >> 2) & 63, jp = i & 3;
        const int n = nt * 16 + (ln & 15);
        const int k = ks * 32 + (ln >> 4) * 8 + jp * 2;
        pWin[i] = pack2bf(Win[k * HID + n], Win[(k + 1) * HID + n]);
    } else if (i < 10240) {               // 3 layers: 4 ntiles x 2 ksteps each
        int j = i - 4096;
        const int l = j >> 11; j &= 2047;
        const int nt = j >> 9, ks = (j >> 8) & 1, ln = (j >> 2) & 63, jp = j & 3;
        const int n = nt * 16 + (ln & 15);
        const int k = ks * 32 + (ln >> 4) * 8 + jp * 2;
        const float* w = Wl + (size_t)l * HID * HID;
        pWl[i - 4096] = pack2bf(w[k * HID + n], w[(k + 1) * HID + n]);
    } else if (i < 11776) {               // W_cls: 3 ntiles (48 cols, pad) x 2 ks
        const int j = i - 10240;
        const int nt = j >> 9, ks = (j >> 8) & 1, ln = (j >> 2) & 63, jp = j & 3;
        const int n = nt * 16 + (ln & 15);
        const int k = ks * 32 + (ln >> 4) * 8 + jp * 2;
        pWc[j] = (n < NCLS) ? pack2bf(Wc[k * NCLS + n], Wc[(k + 1) * NCLS + n]) : 0u;
    }
}

// ------- K1 (MFMA): Hbf = relu(x @ W_in + b_in) ----------------------------
__global__ __launch_bounds__(256) void k_in_gemm(
    const float* __restrict__ x, const unsigned* __restrict__ pWin,
    const float* __restrict__ b, unsigned short* __restrict__ H0)
{
    __shared__ unsigned sxp[64][68];      // padded: 2-way bank aliasing only
    __shared__ unsigned sB[4][4][64][4];  // 16 KB
    const int t = threadIdx.x;
    for (int i = t; i < 1024; i += 256)
        ((uint4*)sB)[i] = ((const uint4*)pWin)[i];
    const int r0 = blockIdx.x * 64;
    for (int i = t; i < 4096; i += 256) {
        const int r = i >> 6, c = i & 63;
        const int gr = r0 + r;
        float2 v; v.x = 0.f; v.y = 0.f;
        if (gr < N_NODES) v = *(const float2*)&x[(size_t)gr * IN_DIM + 2 * c];
        sxp[r][c] = pack2bf(v.x, v.y);
    }
    __syncthreads();

    const int lane = t & 63;
    const int w    = t >> 6;
    const int tile = blockIdx.x * 4 + w;
    if (tile >= NTILES_M) return;
    const int quad = lane >> 4;
    const int mrow = (w << 4) + (lane & 15);

    f32x4 acc0 = {0.f, 0.f, 0.f, 0.f};
    f32x4 acc1 = {0.f, 0.f, 0.f, 0.f};
    f32x4 acc2 = {0.f, 0.f, 0.f, 0.f};
    f32x4 acc3 = {0.f, 0.f, 0.f, 0.f};
    #pragma unroll
    for (int ks = 0; ks < 4; ++ks) {
        const bf16x8 a = *(const bf16x8*)&sxp[mrow][ks * 16 + quad * 4];
        acc0 = __builtin_amdgcn_mfma_f32_16x16x32_bf16(a, *(const bf16x8*)&sB[0][ks][lane][0], acc0, 0, 0, 0);
        acc1 = __builtin_amdgcn_mfma_f32_16x16x32_bf16(a, *(const bf16x8*)&sB[1][ks][lane][0], acc1, 0, 0, 0);
        acc2 = __builtin_amdgcn_mfma_f32_16x16x32_bf16(a, *(const bf16x8*)&sB[2][ks][lane][0], acc2, 0, 0, 0);
        acc3 = __builtin_amdgcn_mfma_f32_16x16x32_bf16(a, *(const bf16x8*)&sB[3][ks][lane][0], acc3, 0, 0, 0);
    }

    const int colg = lane & 15;
    const int nodeb = tile * 16 + quad * 4;
    const float bv0 = b[     colg];
    const float bv1 = b[16 + colg];
    const float bv2 = b[32 + colg];
    const float bv3 = b[48 + colg];
    #pragma unroll
    for (int r = 0; r < 4; ++r) {
        const size_t ob = (size_t)(nodeb + r) * HID;
        H0[ob      + colg] = f2bf(fmaxf(acc0[r] + bv0, 0.f));
        H0[ob + 16 + colg] = f2bf(fmaxf(acc1[r] + bv1, 0.f));
        H0[ob + 32 + colg] = f2bf(fmaxf(acc2[r] + bv2, 0.f));
        H0[ob + 48 + colg] = f2bf(fmaxf(acc3[r] + bv3, 0.f));
    }
}

// ---------------- bucket partition (782 small tiles for occupancy) ---------
__global__ __launch_bounds__(256) void k_part(
    const int* __restrict__ ei, int* __restrict__ cursor, int* __restrict__ pairs)
{
    __shared__ int lh[NBUCK];
    __shared__ int lbase[NBUCK];
    __shared__ int lcnt[NBUCK];
    const int t = threadIdx.x;
    for (int i = t; i < NBUCK; i += 256) { lh[i] = 0; lcnt[i] = 0; }
    __syncthreads();
    const int e0 = blockIdx.x * TILE_E;
    for (int k = 0; k < TILE_E; k += 256) {
        int e = e0 + k + t;
        if (e < E_NUM) atomicAdd(&lh[ei[E_NUM + e] >> 7], 1);
    }
    __syncthreads();
    for (int i = t; i < NBUCK; i += 256)
        lbase[i] = lh[i] ? atomicAdd(&cursor[i], lh[i]) : 0;
    __syncthreads();
    for (int k = 0; k < TILE_E; k += 256) {
        int e = e0 + k + t;
        if (e < E_NUM) {
            int src = ei[e];
            int dst = ei[E_NUM + e];
            int b   = dst >> 7;
            int r   = lbase[b] + atomicAdd(&lcnt[b], 1);
            if (r < BCAP) pairs[b * BCAP + r] = (src << 7) | (dst & 127);
        }
    }
}

// one block per bucket: per-node CSR with per-node pad-to-8 (sentinel ZROW).
// Pad slots are filled per-node (<=7 writes each) instead of a full-range
// pre-fill: the pad range [ex+cnt, ex+pc) is disjoint from the scatter range.
__global__ __launch_bounds__(256) void k_bsort(
    const int* __restrict__ cursor, const int* __restrict__ pairs,
    int* __restrict__ srcs, int* __restrict__ row_start, int* __restrict__ row_end)
{
    __shared__ int cnt[128];
    __shared__ int sc[128];
    __shared__ int cur[128];
    const int t = threadIdx.x;
    const int b = blockIdx.x;
    const int beg = b * BCAP;
    const int n_e = min(cursor[b], BCAP);
    if (t < 128) cnt[t] = 0;
    __syncthreads();
    for (int i = t; i < n_e; i += 256)
        atomicAdd(&cnt[pairs[beg + i] & 127], 1);
    __syncthreads();
    if (t < 128) sc[t] = (cnt[t] + 7) & ~7;
    __syncthreads();
    for (int off = 1; off < 128; off <<= 1) {
        int a = (t < 128 && t >= off) ? sc[t - off] : 0;
        __syncthreads();
        if (t < 128) sc[t] += a;
        __syncthreads();
    }
    const int node0 = b << 7;
    if (t < 128) {
        const int pc = (cnt[t] + 7) & ~7;
        const int ex = sc[t] - pc;
        cur[t] = ex;
        const int node = node0 + t;
        if (node < N_NODES) {
            const int rs = beg + ex;
            row_start[node] = rs;
            row_end  [node] = min(rs + pc, beg + BCAP);
        }
        // per-node sentinel pad fill (disjoint from scatter range below)
        const int fb = beg + ex + cnt[t];
        const int fe = min(beg + ex + pc, beg + BCAP);
        for (int i = fb; i < fe; ++i) srcs[i] = ZROW;
    }
    __syncthreads();
    for (int i = t; i < n_e; i += 256) {
        int p = pairs[beg + i];
        int r = atomicAdd(&cur[p & 127], 1);
        if (r < BCAP) srcs[beg + r] = p >> 7;
    }
}

// ------- fused: U = H[n] + sum H[src]  then  Hout = relu(U @ W + b) --------
__global__ __launch_bounds__(256) void k_gather_gemm(
    const int* __restrict__ row_start, const int* __restrict__ row_end,
    const int* __restrict__ srcs,
    const unsigned short* __restrict__ Hin, const unsigned* __restrict__ pWl,
    const float* __restrict__ bl, unsigned short* __restrict__ Hout)
{
    __shared__ unsigned sup[16][36];      // packed bf16 U; pad -> 2-way banks
    const int t = threadIdx.x;
    const int lane = t & 63;
    const int w    = t >> 6;
    const int half = lane >> 5;
    const int fl   = lane & 31;
    const int row0 = blockIdx.x * 16;
    const int n0   = row0 + (w << 2);

    int i0 = __builtin_amdgcn_readfirstlane(row_start[n0    ]);
    int i1 = __builtin_amdgcn_readfirstlane(row_start[n0 + 1]);
    int i2 = __builtin_amdgcn_readfirstlane(row_start[n0 + 2]);
    int i3 = __builtin_amdgcn_readfirstlane(row_start[n0 + 3]);
    const int e0 = __builtin_amdgcn_readfirstlane(row_end[n0    ]);
    const int e1 = __builtin_amdgcn_readfirstlane(row_end[n0 + 1]);
    const int e2 = __builtin_amdgcn_readfirstlane(row_end[n0 + 2]);
    const int e3 = __builtin_amdgcn_readfirstlane(row_end[n0 + 3]);

    float ax0 = 0.f, ay0 = 0.f, ax1 = 0.f, ay1 = 0.f;
    float ax2 = 0.f, ay2 = 0.f, ax3 = 0.f, ay3 = 0.f;

    while (i0 < e0 || i1 < e1 || i2 < e2 || i3 < e3) {
        const bool b0 = i0 < e0, b1 = i1 < e1, b2 = i2 < e2, b3 = i3 < e3;
        int sA0=0,sA1=0,sA2=0,sA3=0, sB0=0,sB1=0,sB2=0,sB3=0;
        int sC0=0,sC1=0,sC2=0,sC3=0, sD0=0,sD1=0,sD2=0,sD3=0;
        if (b0) { const int p = i0 + half; sA0=srcs[p]; sA1=srcs[p+2]; sA2=srcs[p+4]; sA3=srcs[p+6]; }
        if (b1) { const int p = i1 + half; sB0=srcs[p]; sB1=srcs[p+2]; sB2=srcs[p+4]; sB3=srcs[p+6]; }
        if (b2) { const int p = i2 + half; sC0=srcs[p]; sC1=srcs[p+2]; sC2=srcs[p+4]; sC3=srcs[p+6]; }
        if (b3) { const int p = i3 + half; sD0=srcs[p]; sD1=srcs[p+2]; sD2=srcs[p+4]; sD3=srcs[p+6]; }
        unsigned uA0=0,uA1=0,uA2=0,uA3=0, uB0=0,uB1=0,uB2=0,uB3=0;
        unsigned uC0=0,uC1=0,uC2=0,uC3=0, uD0=0,uD1=0,uD2=0,uD3=0;
        if (b0) {
            uA0 = *(const unsigned*)(Hin + (size_t)sA0 * HID + 2 * fl);
            uA1 = *(const unsigned*)(Hin + (size_t)sA1 * HID + 2 * fl);
            uA2 = *(const unsigned*)(Hin + (size_t)sA2 * HID + 2 * fl);
            uA3 = *(const unsigned*)(Hin + (size_t)sA3 * HID + 2 * fl);
        }
        if (b1) {
            uB0 = *(const unsigned*)(Hin + (size_t)sB0 * HID + 2 * fl);
            uB1 = *(const unsigned*)(Hin + (size_t)sB1 * HID + 2 * fl);
            uB2 = *(const unsigned*)(Hin + (size_t)sB2 * HID + 2 * fl);
            uB3 = *(const unsigned*)(Hin + (size_t)sB3 * HID + 2 * fl);
        }
        if (b2) {
            uC0 = *(const unsigned*)(Hin + (size_t)sC0 * HID + 2 * fl);
            uC1 = *(const unsigned*)(Hin + (size_t)sC1 * HID + 2 * fl);
            uC2 = *(const unsigned*)(Hin + (size_t)sC2 * HID + 2 * fl);
            uC3 = *(const unsigned*)(Hin + (size_t)sC3 * HID + 2 * fl);
        }
        if (b3) {
            uD0 = *(const unsigned*)(Hin + (size_t)sD0 * HID + 2 * fl);
            uD1 = *(const unsigned*)(Hin + (size_t)sD1 * HID + 2 * fl);
            uD2 = *(const unsigned*)(Hin + (size_t)sD2 * HID + 2 * fl);
            uD3 = *(const unsigned*)(Hin + (size_t)sD3 * HID + 2 * fl);
        }
        if (b0) {
            ax0 += bflo(uA0); ay0 += bfhi(uA0);
            ax0 += bflo(uA1); ay0 += bfhi(uA1);
            ax0 += bflo(uA2); ay0 += bfhi(uA2);
            ax0 += bflo(uA3); ay0 += bfhi(uA3);
            i0 += 8;
        }
        if (b1) {
            ax1 += bflo(uB0); ay1 += bfhi(uB0);
            ax1 += bflo(uB1); ay1 += bfhi(uB1);
            ax1 += bflo(uB2); ay1 += bfhi(uB2);
            ax1 += bflo(uB3); ay1 += bfhi(uB3);
            i1 += 8;
        }
        if (b2) {
            ax2 += bflo(uC0); ay2 += bfhi(uC0);
            ax2 += bflo(uC1); ay2 += bfhi(uC1);
            ax2 += bflo(uC2); ay2 += bfhi(uC2);
            ax2 += bflo(uC3); ay2 += bfhi(uC3);
            i2 += 8;
        }
        if (b3) {
            ax3 += bflo(uD0); ay3 += bfhi(uD0);
            ax3 += bflo(uD1); ay3 += bfhi(uD1);
            ax3 += bflo(uD2); ay3 += bfhi(uD2);
            ax3 += bflo(uD3); ay3 += bfhi(uD3);
            i3 += 8;
        }
    }

    ax0 += __shfl_xor(ax0, 32, 64); ay0 += __shfl_xor(ay0, 32, 64);
    ax1 += __shfl_xor(ax1, 32, 64); ay1 += __shfl_xor(ay1, 32, 64);
    ax2 += __shfl_xor(ax2, 32, 64); ay2 += __shfl_xor(ay2, 32, 64);
    ax3 += __shfl_xor(ax3, 32, 64); ay3 += __shfl_xor(ay3, 32, 64);
    const unsigned us0 = *(const unsigned*)(Hin + (size_t)(n0    ) * HID + 2 * fl);
    const unsigned us1 = *(const unsigned*)(Hin + (size_t)(n0 + 1) * HID + 2 * fl);
    const unsigned us2 = *(const unsigned*)(Hin + (size_t)(n0 + 2) * HID + 2 * fl);
    const unsigned us3 = *(const unsigned*)(Hin + (size_t)(n0 + 3) * HID + 2 * fl);
    ax0 += bflo(us0); ay0 += bfhi(us0);
    ax1 += bflo(us1); ay1 += bfhi(us1);
    ax2 += bflo(us2); ay2 += bfhi(us2);
    ax3 += bflo(us3); ay3 += bfhi(us3);
    if (half == 0) {
        sup[(w << 2)    ][fl] = pack2bf(ax0, ay0);
        sup[(w << 2) + 1][fl] = pack2bf(ax1, ay1);
        sup[(w << 2) + 2][fl] = pack2bf(ax2, ay2);
        sup[(w << 2) + 3][fl] = pack2bf(ax3, ay3);
    }
    __syncthreads();

    // MFMA tail: wave w -> output cols [w*16, w*16+16); B-frags from global
    const int quad = lane >> 4;
    const int m    = lane & 15;
    const bf16x8* pb = (const bf16x8*)pWl;
    f32x4 acc = {0.f, 0.f, 0.f, 0.f};
    #pragma unroll
    for (int ks = 0; ks < 2; ++ks) {
        const bf16x8 a  = *(const bf16x8*)&sup[m][ks * 16 + quad * 4];
        const bf16x8 bb = pb[((w << 1) + ks) * 64 + lane];
        acc = __builtin_amdgcn_mfma_f32_16x16x32_bf16(a, bb, acc, 0, 0, 0);
    }
    const int jc = w * 16 + m;
    const float bv = bl[jc];
    #pragma unroll
    for (int r = 0; r < 4; ++r) {
        const int node = row0 + quad * 4 + r;
        Hout[(size_t)node * HID + jc] = f2bf(fmaxf(acc[r] + bv, 0.f));
    }
}

// ---------------- classifier: pure MFMA, no LDS, no barriers ---------------
__global__ __launch_bounds__(256) void k_cls(
    const unsigned* __restrict__ pWc, const float* __restrict__ bc,
    const unsigned short* __restrict__ H, float* __restrict__ out)
{
    const int t = threadIdx.x;
    const int lane = t & 63;
    const int w    = t >> 6;
    const int quad = lane >> 4;
    const int m    = lane & 15;
    const int row  = blockIdx.x * 64 + w * 16 + m;   // A row for this lane
    const bf16x8* pb = (const bf16x8*)pWc;

    f32x4 acc0 = {0.f, 0.f, 0.f, 0.f};
    f32x4 acc1 = {0.f, 0.f, 0.f, 0.f};
    f32x4 acc2 = {0.f, 0.f, 0.f, 0.f};
    #pragma unroll
    for (int ks = 0; ks < 2; ++ks) {
        const bf16x8 a = *(const bf16x8*)(H + (size_t)row * HID + ks * 32 + quad * 8);
        acc0 = __builtin_amdgcn_mfma_f32_16x16x32_bf16(a, pb[(0 * 2 + ks) * 64 + lane], acc0, 0, 0, 0);
        acc1 = __builtin_amdgcn_mfma_f32_16x16x32_bf16(a, pb[(1 * 2 + ks) * 64 + lane], acc1, 0, 0, 0);
        acc2 = __builtin_amdgcn_mfma_f32_16x16x32_bf16(a, pb[(2 * 2 + ks) * 64 + lane], acc2, 0, 0, 0);
    }
    const int nodeb = blockIdx.x * 64 + w * 16 + quad * 4;
    const float bv0 = bc[m];
    const float bv1 = bc[16 + m];
    const float bv2 = (32 + m < NCLS) ? bc[32 + m] : 0.f;
    #pragma unroll
    for (int r = 0; r < 4; ++r) {
        const int node = nodeb + r;
        if (node < N_NODES) {
            out[(size_t)node * NCLS + m     ] = acc0[r] + bv0;
            out[(size_t)node * NCLS + 16 + m] = acc1[r] + bv1;
            if (32 + m < NCLS)
                out[(size_t)node * NCLS + 32 + m] = acc2[r] + bv2;
        }
    }
}

extern "C" void kernel_launch(void* const* d_in, const int* in_sizes, int n_in,
                              void* d_out, int out_size, void* d_ws, size_t ws_size,
                              hipStream_t stream)
{
    const float* x        = (const float*)d_in[0];
    const int*   ei       = (const int*)  d_in[1];
    const float* W_in     = (const float*)d_in[2];
    const float* b_in     = (const float*)d_in[3];
    const float* W_layers = (const float*)d_in[4];
    const float* b_layers = (const float*)d_in[5];
    const float* W_cls    = (const float*)d_in[6];
    const float* b_cls    = (const float*)d_in[7];
    float* out = (float*)d_out;

    // ws layout (~45.3 MB): H0, H1, build scratch, prepped weight fragments
    unsigned short* H0 = (unsigned short*)d_ws;
    unsigned short* H1 = H0 + (size_t)(N_NODES + 1) * HID;
    int* wsp       = (int*)(H1 + (size_t)(N_NODES + 1) * HID);
    int* pairs     = wsp;                         // NBUCK*BCAP = 2.40M ints
    int* srcs      = wsp + NBUCK * BCAP;          // 2.40M ints
    int* row_start = wsp + 2 * NBUCK * BCAP;      // 100000 (pad 100096)
    int* row_end   = row_start + 100096;          // 100000
    int* cursor    = row_end + 100096;            // 782 (pad 1024)
    unsigned* pWin = (unsigned*)(cursor + 1024);  // 4096
    unsigned* pWl  = pWin + 4096;                 // 6144 (3 layers x 2048)
    unsigned* pWc  = pWl + 6144;                  // 1536

    const int gemm_blocks = N_NODES / 16;         // 6250 (gather)
    const int in_blocks   = (NTILES_M + 3) / 4;   // 1563 (in_gemm, cls)

    k_prep   <<<46, 256, 0, stream>>>(W_in, W_layers, W_cls, pWin, pWl, pWc,
                                      cursor, H0, H1);
    k_part   <<<NTILE, 256, 0, stream>>>(ei, cursor, pairs);
    k_bsort  <<<NBUCK, 256, 0, stream>>>(cursor, pairs, srcs, row_start, row_end);
    k_in_gemm<<<in_blocks, 256, 0, stream>>>(x, pWin, b_in, H0);

    unsigned short* Hi = H0; unsigned short* Ho = H1;
    for (int i = 0; i < 3; ++i) {
        k_gather_gemm<<<gemm_blocks, 256, 0, stream>>>(
            row_start, row_end, srcs, Hi,
            pWl + (size_t)i * 2048, b_layers + (size_t)i * HID, Ho);
        unsigned short* tmp = Hi; Hi = Ho; Ho = tmp;
    }
    k_cls<<<in_blocks, 256, 0, stream>>>(pWc, b_cls, Hi, out);
}

// Round 17
// 275.984 us; speedup vs baseline: 1.0611x; 1.0611x over previous
//
#include <hip/hip_runtime.h>
#include <hip/hip_bf16.h>

#define N_NODES 100000
#define E_NUM   1600000
#define IN_DIM  128
#define HID     64
#define NCLS    40
#define NBUCK   782      // ceil(N_NODES/128); bucket b owns nodes [b*128, b*128+128)
#define TILE_E  8192     // r15/r16 A/B: big tiles win (write amplification at 2048)
#define NTILE   196      // ceil(E_NUM / TILE_E)
#define BCAP    3072     // per-bucket capacity incl. pad-to-8
#define ZROW    N_NODES  // sentinel node whose H row is all zeros
#define NTILES_M 6250    // N_NODES / 16
#define IN_BLOCKS 1563   // ceil(NTILES_M / 4)

typedef __attribute__((ext_vector_type(8))) short bf16x8;
typedef __attribute__((ext_vector_type(4))) float f32x4;

// bf16 helpers
static __device__ __forceinline__ float bflo(unsigned u) {
    return __uint_as_float(u << 16);
}
static __device__ __forceinline__ float bfhi(unsigned u) {
    return __uint_as_float(u & 0xFFFF0000u);
}
static __device__ __forceinline__ unsigned short f2bf(float f) {
    unsigned u = __float_as_uint(f);
    u += 0x7FFFu + ((u >> 16) & 1u);     // round-to-nearest-even
    return (unsigned short)(u >> 16);
}
static __device__ __forceinline__ unsigned pack2bf(float lo, float hi) {
    return (unsigned)f2bf(lo) | ((unsigned)f2bf(hi) << 16);
}

// ------ k_prep: pre-swizzle ALL weights into B-fragment order + init -------
__global__ void k_prep(const float* __restrict__ Win, const float* __restrict__ Wl,
                       const float* __restrict__ Wc, unsigned* __restrict__ pWin,
                       unsigned* __restrict__ pWl, unsigned* __restrict__ pWc,
                       int* __restrict__ cursor, unsigned short* __restrict__ H0,
                       unsigned short* __restrict__ H1)
{
    const int t = threadIdx.x;
    if (blockIdx.x == 0) {
        for (int i = t; i < NBUCK; i += 256) cursor[i] = 0;
        if (t < 32) {
            ((unsigned*)(H0 + (size_t)ZROW * HID))[t] = 0;
            ((unsigned*)(H1 + (size_t)ZROW * HID))[t] = 0;
        }
    }
    int i = blockIdx.x * 256 + t;
    if (i < 4096) {                       // W_in: 4 ntiles x 4 ksteps
        const int nt = i >> 10, ks = (i >> 8) & 3, ln = (i >> 2) & 63, jp = i & 3;
        const int n = nt * 16 + (ln & 15);
        const int k = ks * 32 + (ln >> 4) * 8 + jp * 2;
        pWin[i] = pack2bf(Win[k * HID + n], Win[(k + 1) * HID + n]);
    } else if (i < 10240) {               // 3 layers: 4 ntiles x 2 ksteps each
        int j = i - 4096;
        const int l = j >> 11; j &= 2047;
        const int nt = j >> 9, ks = (j >> 8) & 1, ln = (j >> 2) & 63, jp = j & 3;
        const int n = nt * 16 + (ln & 15);
        const int k = ks * 32 + (ln >> 4) * 8 + jp * 2;
        const float* w = Wl + (size_t)l * HID * HID;
        pWl[i - 4096] = pack2bf(w[k * HID + n], w[(k + 1) * HID + n]);
    } else if (i < 11776) {               // W_cls: 3 ntiles (48 cols, pad) x 2 ks
        const int j = i - 10240;
        const int nt = j >> 9, ks = (j >> 8) & 1, ln = (j >> 2) & 63, jp = j & 3;
        const int n = nt * 16 + (ln & 15);
        const int k = ks * 32 + (ln >> 4) * 8 + jp * 2;
        pWc[j] = (n < NCLS) ? pack2bf(Wc[k * NCLS + n], Wc[(k + 1) * NCLS + n]) : 0u;
    }
}

// ------ fused: blocks 0..195 partition edges; blocks 196+ do in_gemm -------
// part is latency-bound (VALU 2%), in_gemm is MFMA-bound; co-resident blocks
// overlap (m114: time = max, not sum). LDS overlaid via union.
__global__ __launch_bounds__(256) void k_build_ingemm(
    const int* __restrict__ ei, int* __restrict__ cursor, int* __restrict__ pairs,
    const float* __restrict__ x, const unsigned* __restrict__ pWin,
    const float* __restrict__ b, unsigned short* __restrict__ H0)
{
    __shared__ union SM {
        struct { int lh[NBUCK], lbase[NBUCK], lcnt[NBUCK]; } p;   // 9.4 KB
        struct { unsigned sxp[64][68]; unsigned sB[4][4][64][4]; } g; // 33.8 KB
    } sm;
    const int t = threadIdx.x;

    if (blockIdx.x < NTILE) {
        // ---------------- partition tile (TILE_E = 8192) ----------------
        int* lh = sm.p.lh; int* lbase = sm.p.lbase; int* lcnt = sm.p.lcnt;
        for (int i = t; i < NBUCK; i += 256) { lh[i] = 0; lcnt[i] = 0; }
        __syncthreads();
        const int e0 = blockIdx.x * TILE_E;
        for (int k = 0; k < TILE_E; k += 256) {
            int e = e0 + k + t;
            if (e < E_NUM) atomicAdd(&lh[ei[E_NUM + e] >> 7], 1);
        }
        __syncthreads();
        for (int i = t; i < NBUCK; i += 256)
            lbase[i] = lh[i] ? atomicAdd(&cursor[i], lh[i]) : 0;
        __syncthreads();
        for (int k = 0; k < TILE_E; k += 256) {
            int e = e0 + k + t;
            if (e < E_NUM) {
                int src = ei[e];
                int dst = ei[E_NUM + e];
                int bkt = dst >> 7;
                int r   = lbase[bkt] + atomicAdd(&lcnt[bkt], 1);
                if (r < BCAP) pairs[bkt * BCAP + r] = (src << 7) | (dst & 127);
            }
        }
        return;
    }

    // ---------------- in_gemm block (MFMA) ----------------
    const int blk = blockIdx.x - NTILE;
    for (int i = t; i < 1024; i += 256)
        ((uint4*)sm.g.sB)[i] = ((const uint4*)pWin)[i];
    const int r0 = blk * 64;
    for (int i = t; i < 4096; i += 256) {
        const int r = i >> 6, c = i & 63;
        const int gr = r0 + r;
        float2 v; v.x = 0.f; v.y = 0.f;
        if (gr < N_NODES) v = *(const float2*)&x[(size_t)gr * IN_DIM + 2 * c];
        sm.g.sxp[r][c] = pack2bf(v.x, v.y);
    }
    __syncthreads();

    const int lane = t & 63;
    const int w    = t >> 6;
    const int tile = blk * 4 + w;
    if (tile >= NTILES_M) return;
    const int quad = lane >> 4;
    const int mrow = (w << 4) + (lane & 15);

    f32x4 acc0 = {0.f, 0.f, 0.f, 0.f};
    f32x4 acc1 = {0.f, 0.f, 0.f, 0.f};
    f32x4 acc2 = {0.f, 0.f, 0.f, 0.f};
    f32x4 acc3 = {0.f, 0.f, 0.f, 0.f};
    #pragma unroll
    for (int ks = 0; ks < 4; ++ks) {
        const bf16x8 a = *(const bf16x8*)&sm.g.sxp[mrow][ks * 16 + quad * 4];
        acc0 = __builtin_amdgcn_mfma_f32_16x16x32_bf16(a, *(const bf16x8*)&sm.g.sB[0][ks][lane][0], acc0, 0, 0, 0);
        acc1 = __builtin_amdgcn_mfma_f32_16x16x32_bf16(a, *(const bf16x8*)&sm.g.sB[1][ks][lane][0], acc1, 0, 0, 0);
        acc2 = __builtin_amdgcn_mfma_f32_16x16x32_bf16(a, *(const bf16x8*)&sm.g.sB[2][ks][lane][0], acc2, 0, 0, 0);
        acc3 = __builtin_amdgcn_mfma_f32_16x16x32_bf16(a, *(const bf16x8*)&sm.g.sB[3][ks][lane][0], acc3, 0, 0, 0);
    }

    const int colg = lane & 15;
    const int nodeb = tile * 16 + quad * 4;
    const float bv0 = b[     colg];
    const float bv1 = b[16 + colg];
    const float bv2 = b[32 + colg];
    const float bv3 = b[48 + colg];
    #pragma unroll
    for (int r = 0; r < 4; ++r) {
        const size_t ob = (size_t)(nodeb + r) * HID;
        H0[ob      + colg] = f2bf(fmaxf(acc0[r] + bv0, 0.f));
        H0[ob + 16 + colg] = f2bf(fmaxf(acc1[r] + bv1, 0.f));
        H0[ob + 32 + colg] = f2bf(fmaxf(acc2[r] + bv2, 0.f));
        H0[ob + 48 + colg] = f2bf(fmaxf(acc3[r] + bv3, 0.f));
    }
}

// one block per bucket: per-node CSR with per-node pad-to-8 (sentinel ZROW)
__global__ __launch_bounds__(256) void k_bsort(
    const int* __restrict__ cursor, const int* __restrict__ pairs,
    int* __restrict__ srcs, int* __restrict__ row_start, int* __restrict__ row_end)
{
    __shared__ int cnt[128];
    __shared__ int sc[128];
    __shared__ int cur[128];
    const int t = threadIdx.x;
    const int b = blockIdx.x;
    const int beg = b * BCAP;
    const int n_e = min(cursor[b], BCAP);
    if (t < 128) cnt[t] = 0;
    __syncthreads();
    for (int i = t; i < n_e; i += 256)
        atomicAdd(&cnt[pairs[beg + i] & 127], 1);
    __syncthreads();
    if (t < 128) sc[t] = (cnt[t] + 7) & ~7;
    __syncthreads();
    for (int off = 1; off < 128; off <<= 1) {
        int a = (t < 128 && t >= off) ? sc[t - off] : 0;
        __syncthreads();
        if (t < 128) sc[t] += a;
        __syncthreads();
    }
    const int node0 = b << 7;
    if (t < 128) {
        const int pc = (cnt[t] + 7) & ~7;
        const int ex = sc[t] - pc;
        cur[t] = ex;
        const int node = node0 + t;
        if (node < N_NODES) {
            const int rs = beg + ex;
            row_start[node] = rs;
            row_end  [node] = min(rs + pc, beg + BCAP);
        }
        const int fb = beg + ex + cnt[t];
        const int fe = min(beg + ex + pc, beg + BCAP);
        for (int i = fb; i < fe; ++i) srcs[i] = ZROW;
    }
    __syncthreads();
    for (int i = t; i < n_e; i += 256) {
        int p = pairs[beg + i];
        int r = atomicAdd(&cur[p & 127], 1);
        if (r < BCAP) srcs[beg + r] = p >> 7;
    }
}

// ---- shared gather phase: fills sup[16][36] with packed-bf16 U rows -------
static __device__ __forceinline__ void gather_tile(
    const int* __restrict__ row_start, const int* __restrict__ row_end,
    const int* __restrict__ srcs, const unsigned short* __restrict__ Hin,
    unsigned (*sup)[36], int row0, int t)
{
    const int lane = t & 63;
    const int w    = t >> 6;
    const int half = lane >> 5;
    const int fl   = lane & 31;
    const int n0   = row0 + (w << 2);

    int i0 = __builtin_amdgcn_readfirstlane(row_start[n0    ]);
    int i1 = __builtin_amdgcn_readfirstlane(row_start[n0 + 1]);
    int i2 = __builtin_amdgcn_readfirstlane(row_start[n0 + 2]);
    int i3 = __builtin_amdgcn_readfirstlane(row_start[n0 + 3]);
    const int e0 = __builtin_amdgcn_readfirstlane(row_end[n0    ]);
    const int e1 = __builtin_amdgcn_readfirstlane(row_end[n0 + 1]);
    const int e2 = __builtin_amdgcn_readfirstlane(row_end[n0 + 2]);
    const int e3 = __builtin_amdgcn_readfirstlane(row_end[n0 + 3]);

    float ax0 = 0.f, ay0 = 0.f, ax1 = 0.f, ay1 = 0.f;
    float ax2 = 0.f, ay2 = 0.f, ax3 = 0.f, ay3 = 0.f;

    while (i0 < e0 || i1 < e1 || i2 < e2 || i3 < e3) {
        const bool b0 = i0 < e0, b1 = i1 < e1, b2 = i2 < e2, b3 = i3 < e3;
        int sA0=0,sA1=0,sA2=0,sA3=0, sB0=0,sB1=0,sB2=0,sB3=0;
        int sC0=0,sC1=0,sC2=0,sC3=0, sD0=0,sD1=0,sD2=0,sD3=0;
        if (b0) { const int p = i0 + half; sA0=srcs[p]; sA1=srcs[p+2]; sA2=srcs[p+4]; sA3=srcs[p+6]; }
        if (b1) { const int p = i1 + half; sB0=srcs[p]; sB1=srcs[p+2]; sB2=srcs[p+4]; sB3=srcs[p+6]; }
        if (b2) { const int p = i2 + half; sC0=srcs[p]; sC1=srcs[p+2]; sC2=srcs[p+4]; sC3=srcs[p+6]; }
        if (b3) { const int p = i3 + half; sD0=srcs[p]; sD1=srcs[p+2]; sD2=srcs[p+4]; sD3=srcs[p+6]; }
        unsigned uA0=0,uA1=0,uA2=0,uA3=0, uB0=0,uB1=0,uB2=0,uB3=0;
        unsigned uC0=0,uC1=0,uC2=0,uC3=0, uD0=0,uD1=0,uD2=0,uD3=0;
        if (b0) {
            uA0 = *(const unsigned*)(Hin + (size_t)sA0 * HID + 2 * fl);
            uA1 = *(const unsigned*)(Hin + (size_t)sA1 * HID + 2 * fl);
            uA2 = *(const unsigned*)(Hin + (size_t)sA2 * HID + 2 * fl);
            uA3 = *(const unsigned*)(Hin + (size_t)sA3 * HID + 2 * fl);
        }
        if (b1) {
            uB0 = *(const unsigned*)(Hin + (size_t)sB0 * HID + 2 * fl);
            uB1 = *(const unsigned*)(Hin + (size_t)sB1 * HID + 2 * fl);
            uB2 = *(const unsigned*)(Hin + (size_t)sB2 * HID + 2 * fl);
            uB3 = *(const unsigned*)(Hin + (size_t)sB3 * HID + 2 * fl);
        }
        if (b2) {
            uC0 = *(const unsigned*)(Hin + (size_t)sC0 * HID + 2 * fl);
            uC1 = *(const unsigned*)(Hin + (size_t)sC1 * HID + 2 * fl);
            uC2 = *(const unsigned*)(Hin + (size_t)sC2 * HID + 2 * fl);
            uC3 = *(const unsigned*)(Hin + (size_t)sC3 * HID + 2 * fl);
        }
        if (b3) {
            uD0 = *(const unsigned*)(Hin + (size_t)sD0 * HID + 2 * fl);
            uD1 = *(const unsigned*)(Hin + (size_t)sD1 * HID + 2 * fl);
            uD2 = *(const unsigned*)(Hin + (size_t)sD2 * HID + 2 * fl);
            uD3 = *(const unsigned*)(Hin + (size_t)sD3 * HID + 2 * fl);
        }
        if (b0) {
            ax0 += bflo(uA0); ay0 += bfhi(uA0);
            ax0 += bflo(uA1); ay0 += bfhi(uA1);
            ax0 += bflo(uA2); ay0 += bfhi(uA2);
            ax0 += bflo(uA3); ay0 += bfhi(uA3);
            i0 += 8;
        }
        if (b1) {
            ax1 += bflo(uB0); ay1 += bfhi(uB0);
            ax1 += bflo(uB1); ay1 += bfhi(uB1);
            ax1 += bflo(uB2); ay1 += bfhi(uB2);
            ax1 += bflo(uB3); ay1 += bfhi(uB3);
            i1 += 8;
        }
        if (b2) {
            ax2 += bflo(uC0); ay2 += bfhi(uC0);
            ax2 += bflo(uC1); ay2 += bfhi(uC1);
            ax2 += bflo(uC2); ay2 += bfhi(uC2);
            ax2 += bflo(uC3); ay2 += bfhi(uC3);
            i2 += 8;
        }
        if (b3) {
            ax3 += bflo(uD0); ay3 += bfhi(uD0);
            ax3 += bflo(uD1); ay3 += bfhi(uD1);
            ax3 += bflo(uD2); ay3 += bfhi(uD2);
            ax3 += bflo(uD3); ay3 += bfhi(uD3);
            i3 += 8;
        }
    }

    ax0 += __shfl_xor(ax0, 32, 64); ay0 += __shfl_xor(ay0, 32, 64);
    ax1 += __shfl_xor(ax1, 32, 64); ay1 += __shfl_xor(ay1, 32, 64);
    ax2 += __shfl_xor(ax2, 32, 64); ay2 += __shfl_xor(ay2, 32, 64);
    ax3 += __shfl_xor(ax3, 32, 64); ay3 += __shfl_xor(ay3, 32, 64);
    const unsigned us0 = *(const unsigned*)(Hin + (size_t)(n0    ) * HID + 2 * fl);
    const unsigned us1 = *(const unsigned*)(Hin + (size_t)(n0 + 1) * HID + 2 * fl);
    const unsigned us2 = *(const unsigned*)(Hin + (size_t)(n0 + 2) * HID + 2 * fl);
    const unsigned us3 = *(const unsigned*)(Hin + (size_t)(n0 + 3) * HID + 2 * fl);
    ax0 += bflo(us0); ay0 += bfhi(us0);
    ax1 += bflo(us1); ay1 += bfhi(us1);
    ax2 += bflo(us2); ay2 += bfhi(us2);
    ax3 += bflo(us3); ay3 += bfhi(us3);
    if (half == 0) {
        sup[(w << 2)    ][fl] = pack2bf(ax0, ay0);
        sup[(w << 2) + 1][fl] = pack2bf(ax1, ay1);
        sup[(w << 2) + 2][fl] = pack2bf(ax2, ay2);
        sup[(w << 2) + 3][fl] = pack2bf(ax3, ay3);
    }
}

// ------- layers 1-2: gather + MFMA layer GEMM, write bf16 Hout -------------
__global__ __launch_bounds__(256) void k_gather_gemm(
    const int* __restrict__ row_start, const int* __restrict__ row_end,
    const int* __restrict__ srcs,
    const unsigned short* __restrict__ Hin, const unsigned* __restrict__ pWl,
    const float* __restrict__ bl, unsigned short* __restrict__ Hout)
{
    __shared__ unsigned sup[16][36];
    const int t = threadIdx.x;
    const int row0 = blockIdx.x * 16;
    gather_tile(row_start, row_end, srcs, Hin, sup, row0, t);
    __syncthreads();

    const int lane = t & 63;
    const int w    = t >> 6;
    const int quad = lane >> 4;
    const int m    = lane & 15;
    const bf16x8* pb = (const bf16x8*)pWl;
    f32x4 acc = {0.f, 0.f, 0.f, 0.f};
    #pragma unroll
    for (int ks = 0; ks < 2; ++ks) {
        const bf16x8 a  = *(const bf16x8*)&sup[m][ks * 16 + quad * 4];
        const bf16x8 bb = pb[((w << 1) + ks) * 64 + lane];
        acc = __builtin_amdgcn_mfma_f32_16x16x32_bf16(a, bb, acc, 0, 0, 0);
    }
    const int jc = w * 16 + m;
    const float bv = bl[jc];
    #pragma unroll
    for (int r = 0; r < 4; ++r) {
        const int node = row0 + quad * 4 + r;
        Hout[(size_t)node * HID + jc] = f2bf(fmaxf(acc[r] + bv, 0.f));
    }
}

// ------- layer 3 + classifier fused: no H3 global round-trip ---------------
__global__ __launch_bounds__(256) void k_gather_gemm_cls(
    const int* __restrict__ row_start, const int* __restrict__ row_end,
    const int* __restrict__ srcs,
    const unsigned short* __restrict__ Hin, const unsigned* __restrict__ pWl,
    const float* __restrict__ bl, const unsigned* __restrict__ pWc,
    const float* __restrict__ bc, float* __restrict__ out)
{
    __shared__ unsigned sup[16][36];
    __shared__ unsigned short sh2[16][72];   // relu'd H3 tile, bf16
    const int t = threadIdx.x;
    const int row0 = blockIdx.x * 16;
    gather_tile(row_start, row_end, srcs, Hin, sup, row0, t);
    __syncthreads();

    const int lane = t & 63;
    const int w    = t >> 6;
    const int quad = lane >> 4;
    const int m    = lane & 15;
    const bf16x8* pb = (const bf16x8*)pWl;
    f32x4 acc = {0.f, 0.f, 0.f, 0.f};
    #pragma unroll
    for (int ks = 0; ks < 2; ++ks) {
        const bf16x8 a  = *(const bf16x8*)&sup[m][ks * 16 + quad * 4];
        const bf16x8 bb = pb[((w << 1) + ks) * 64 + lane];
        acc = __builtin_amdgcn_mfma_f32_16x16x32_bf16(a, bb, acc, 0, 0, 0);
    }
    const int jc = w * 16 + m;
    const float bv = bl[jc];
    #pragma unroll
    for (int r = 0; r < 4; ++r)
        sh2[quad * 4 + r][jc] = f2bf(fmaxf(acc[r] + bv, 0.f));
    __syncthreads();

    // classifier: waves 0-2 each compute 16 output cols (48 padded >= NCLS)
    if (w < 3) {
        const bf16x8* pbc = (const bf16x8*)pWc;
        f32x4 c = {0.f, 0.f, 0.f, 0.f};
        #pragma unroll
        for (int ks = 0; ks < 2; ++ks) {
            const bf16x8 a = *(const bf16x8*)&sh2[m][ks * 32 + quad * 8];
            c = __builtin_amdgcn_mfma_f32_16x16x32_bf16(a, pbc[(w * 2 + ks) * 64 + lane], c, 0, 0, 0);
        }
        const int col = w * 16 + m;
        if (col < NCLS) {
            const float bcv = bc[col];
            #pragma unroll
            for (int r = 0; r < 4; ++r)
                out[(size_t)(row0 + quad * 4 + r) * NCLS + col] = c[r] + bcv;
        }
    }
}

extern "C" void kernel_launch(void* const* d_in, const int* in_sizes, int n_in,
                              void* d_out, int out_size, void* d_ws, size_t ws_size,
                              hipStream_t stream)
{
    const float* x        = (const float*)d_in[0];
    const int*   ei       = (const int*)  d_in[1];
    const float* W_in     = (const float*)d_in[2];
    const float* b_in     = (const float*)d_in[3];
    const float* W_layers = (const float*)d_in[4];
    const float* b_layers = (const float*)d_in[5];
    const float* W_cls    = (const float*)d_in[6];
    const float* b_cls    = (const float*)d_in[7];
    float* out = (float*)d_out;

    // ws layout (~45.3 MB): H0, H1, build scratch, prepped weight fragments
    unsigned short* H0 = (unsigned short*)d_ws;
    unsigned short* H1 = H0 + (size_t)(N_NODES + 1) * HID;
    int* wsp       = (int*)(H1 + (size_t)(N_NODES + 1) * HID);
    int* pairs     = wsp;                         // NBUCK*BCAP = 2.40M ints
    int* srcs      = wsp + NBUCK * BCAP;          // 2.40M ints
    int* row_start = wsp + 2 * NBUCK * BCAP;      // 100000 (pad 100096)
    int* row_end   = row_start + 100096;          // 100000
    int* cursor    = row_end + 100096;            // 782 (pad 1024)
    unsigned* pWin = (unsigned*)(cursor + 1024);  // 4096
    unsigned* pWl  = pWin + 4096;                 // 6144 (3 layers x 2048)
    unsigned* pWc  = pWl + 6144;                  // 1536

    const int gemm_blocks = N_NODES / 16;         // 6250 (gather)

    k_prep        <<<46, 256, 0, stream>>>(W_in, W_layers, W_cls, pWin, pWl, pWc,
                                           cursor, H0, H1);
    k_build_ingemm<<<NTILE + IN_BLOCKS, 256, 0, stream>>>(ei, cursor, pairs,
                                                          x, pWin, b_in, H0);
    k_bsort       <<<NBUCK, 256, 0, stream>>>(cursor, pairs, srcs, row_start, row_end);

    k_gather_gemm<<<gemm_blocks, 256, 0, stream>>>(
        row_start, row_end, srcs, H0, pWl,          b_layers,        H1);
    k_gather_gemm<<<gemm_blocks, 256, 0, stream>>>(
        row_start, row_end, srcs, H1, pWl + 2048,   b_layers + HID,  H0);
    k_gather_gemm_cls<<<gemm_blocks, 256, 0, stream>>>(
        row_start, row_end, srcs, H0, pWl + 4096,   b_layers + 2*HID,
        pWc, b_cls, out);
}